// Round 2
// baseline (435.956 us; speedup 1.0000x reference)
//
#include <hip/hip_runtime.h>
#include <cstdint>

typedef unsigned short u16;
typedef float f32x4 __attribute__((ext_vector_type(4)));
typedef __bf16 bf16x8 __attribute__((ext_vector_type(8)));

#define LOG2E 1.44269504088896340736f

// ---------- helpers ----------
__device__ __forceinline__ u16 f2bf(float f) {
    union { float f; unsigned u; } v; v.f = f;
    unsigned r = v.u + 0x7fffu + ((v.u >> 16) & 1u);   // RNE
    return (u16)(r >> 16);
}

__device__ __forceinline__ f32x4 mfma16(bf16x8 a, bf16x8 b, f32x4 c) {
    return __builtin_amdgcn_mfma_f32_16x16x32_bf16(a, b, c, 0, 0, 0);
}

__device__ __forceinline__ void gload_lds16(const void* g, void* l) {
    __builtin_amdgcn_global_load_lds(
        (__attribute__((address_space(1))) unsigned int*)(g),
        (__attribute__((address_space(3))) unsigned int*)(l),
        16, 0, 0);
}

// ---------- constants ----------
#define MB_TOK 8192      // B*S
#define DM 768
#define HH 12
#define DHD 64
#define NWAY 4
#define DFF 3072
#define SEQ 2048
#define NBATCH 4

// ---------- LayerNorm: x f32 [8192,768] -> xn bf16 ----------
__global__ __launch_bounds__(256) void ln_kernel(
    const float* __restrict__ x, const float* __restrict__ g,
    const float* __restrict__ bb, u16* __restrict__ xn)
{
    int row = blockIdx.x, t = threadIdx.x;
    const float* xr = x + (size_t)row * DM;
    float v0 = xr[t], v1 = xr[t + 256], v2 = xr[t + 512];
    float s = v0 + v1 + v2;
    __shared__ float red[4];
    #pragma unroll
    for (int k = 1; k < 64; k <<= 1) s += __shfl_xor(s, k);
    if ((t & 63) == 0) red[t >> 6] = s;
    __syncthreads();
    float mu = (red[0] + red[1] + red[2] + red[3]) * (1.f / 768.f);
    float d0 = v0 - mu, d1 = v1 - mu, d2 = v2 - mu;
    float q = d0 * d0 + d1 * d1 + d2 * d2;
    #pragma unroll
    for (int k = 1; k < 64; k <<= 1) q += __shfl_xor(q, k);
    __syncthreads();
    if ((t & 63) == 0) red[t >> 6] = q;
    __syncthreads();
    float var = (red[0] + red[1] + red[2] + red[3]) * (1.f / 768.f);
    float rs = rsqrtf(var + 1e-6f);
    u16* xo = xn + (size_t)row * DM;
    xo[t]       = f2bf(d0 * rs * g[t]       + bb[t]);
    xo[t + 256] = f2bf(d1 * rs * g[t + 256] + bb[t + 256]);
    xo[t + 512] = f2bf(d2 * rs * g[t + 512] + bb[t + 512]);
}

// ---------- transpose+convert: src f32 [K][N] -> dst bf16 [N][K], batched ----------
__global__ __launch_bounds__(256) void transpose_bf16(
    const float* __restrict__ src, u16* __restrict__ dst, int K, int N)
{
    __shared__ float tl[32][33];
    size_t bofs = (size_t)blockIdx.z * K * N;
    src += bofs; dst += bofs;
    int n0 = blockIdx.x * 32, k0 = blockIdx.y * 32;
    int tx = threadIdx.x, ty = threadIdx.y;
    #pragma unroll
    for (int j = 0; j < 4; ++j)
        tl[ty + j * 8][tx] = src[(size_t)(k0 + ty + j * 8) * N + n0 + tx];
    __syncthreads();
    #pragma unroll
    for (int j = 0; j < 4; ++j)
        dst[(size_t)(n0 + ty + j * 8) * K + k0 + tx] = f2bf(tl[tx][ty + j * 8]);
}

// ---------- bias concat q|k|v ----------
__global__ void concat_bias_kernel(const float* bq, const float* bk,
                                   const float* bv, float* bqkv)
{
    int i = blockIdx.x * 256 + threadIdx.x;
    if (i < 2304) bqkv[i] = i < 768 ? bq[i] : (i < 1536 ? bk[i - 768] : bv[i - 1536]);
}

// ---------- routing: counts, offsets, perm, tile map ----------
__global__ void route_kernel(const int* __restrict__ wl,
                             int* __restrict__ perm, int* __restrict__ eoff,
                             int4* __restrict__ fmap)
{
    __shared__ int cnt[4], cur[4], off[5];
    int tid = threadIdx.x;
    if (tid < 4) cnt[tid] = 0;
    __syncthreads();
    for (int t = tid; t < MB_TOK; t += 256) atomicAdd(&cnt[wl[t] & 3], 1);
    __syncthreads();
    if (tid == 0) {
        off[0] = 0;
        for (int e = 0; e < 4; ++e) off[e + 1] = off[e] + cnt[e];
        int idx = 0;
        for (int e = 0; e < 4; ++e)
            for (int s = 0; s < cnt[e]; s += 128)
                fmap[idx++] = make_int4(e, off[e], s, cnt[e] - s);
        for (; idx < 68; ++idx) fmap[idx] = make_int4(-1, 0, 0, 0);
        for (int e = 0; e < 5; ++e) eoff[e] = off[e];
        for (int e = 0; e < 4; ++e) cur[e] = off[e];
    }
    __syncthreads();
    for (int t = tid; t < MB_TOK; t += 256) {
        int e = wl[t] & 3;
        int pos = atomicAdd(&cur[e], 1);
        perm[pos] = t;
    }
}

// ---------- GEMM: C[M,N] = A[M,K](bf16) * Bt[N,K](bf16)^T + bias ----------
// MODE 0: dense. MODE 1: A rows via perm (FFN1). MODE 2: C rows via perm (FFN2).
template<int MODE, bool RELU, bool RES, bool ST32, bool ST16>
__global__ __launch_bounds__(256, 2) void gemm_bt_kernel(
    const u16* __restrict__ A, const u16* __restrict__ Bt,
    const float* __restrict__ bias, const float* __restrict__ res,
    float* __restrict__ out32, u16* __restrict__ out16,
    int M, int N, int K, int ntn,
    const int* __restrict__ perm, const int4* __restrict__ fmap)
{
    __shared__ __attribute__((aligned(16))) u16 As[128 * 32];
    __shared__ __attribute__((aligned(16))) u16 Bs[128 * 32];
    int tid = threadIdx.x;
    int wv = tid >> 6, ln = tid & 63;
    int bt = blockIdx.x / ntn;
    int tn = (blockIdx.x % ntn) * 128;

    int seg = 0, ms = 0, mb = 128, tm = 0;
    if (MODE != 0) {
        int4 ent = fmap[bt];
        if (ent.x < 0) return;
        seg = ent.y; ms = ent.z; mb = ent.w; if (mb > 128) mb = 128;
        Bt += (size_t)ent.x * N * K;
        bias += ent.x * N;
    } else {
        tm = bt * 128;
    }

    f32x4 acc[4][4];
    #pragma unroll
    for (int i = 0; i < 4; ++i)
        #pragma unroll
        for (int j = 0; j < 4; ++j) acc[i][j] = f32x4{0.f, 0.f, 0.f, 0.f};

    int wr = wv >> 1, wc = wv & 1;
    int lr = ln & 15, hi = ln >> 4;
    int nk = K / 32;

    for (int kk = 0; kk < nk; ++kk) {
        int k0 = kk * 32;
        #pragma unroll
        for (int i = 0; i < 2; ++i) {          // stage A (2 x 1KB per wave)
            int r = (wv * 2 + i) * 16 + (ln >> 2);
            int am = r < mb ? r : (mb - 1);
            size_t arow;
            if (MODE == 1)      arow = (size_t)perm[seg + ms + am];
            else if (MODE == 2) arow = (size_t)(seg + ms + am);
            else                arow = (size_t)(tm + r);
            gload_lds16(A + arow * K + k0 + (ln & 3) * 8, &As[(wv * 2 + i) * 512]);
        }
        #pragma unroll
        for (int i = 0; i < 2; ++i) {          // stage B
            int r = (wv * 2 + i) * 16 + (ln >> 2);
            gload_lds16(Bt + (size_t)(tn + r) * K + k0 + (ln & 3) * 8,
                        &Bs[(wv * 2 + i) * 512]);
        }
        __syncthreads();
        bf16x8 a[4], b[4];
        #pragma unroll
        for (int m = 0; m < 4; ++m)
            a[m] = *(const bf16x8*)&As[(wr * 64 + m * 16 + lr) * 32 + hi * 8];
        #pragma unroll
        for (int n = 0; n < 4; ++n)
            b[n] = *(const bf16x8*)&Bs[(wc * 64 + n * 16 + lr) * 32 + hi * 8];
        #pragma unroll
        for (int m = 0; m < 4; ++m)
            #pragma unroll
            for (int n = 0; n < 4; ++n)
                acc[m][n] = mfma16(a[m], b[n], acc[m][n]);
        __syncthreads();
    }

    // epilogue: C/D layout col=lane&15, row=(lane>>4)*4+i
    #pragma unroll
    for (int m = 0; m < 4; ++m) {
        int rb = wr * 64 + m * 16 + hi * 4;
        #pragma unroll
        for (int n = 0; n < 4; ++n) {
            int gcol = tn + wc * 64 + n * 16 + lr;
            float bvv = bias[gcol];
            #pragma unroll
            for (int i = 0; i < 4; ++i) {
                int rml = rb + i;
                float v = acc[m][n][i] + bvv;
                if (RELU) v = v > 0.f ? v : 0.f;
                if (MODE == 0) {
                    size_t grow = (size_t)(tm + rml);
                    if (RES) v += res[grow * N + gcol];
                    if (ST32) out32[grow * N + gcol] = v;
                    if (ST16) out16[grow * N + gcol] = f2bf(v);
                } else {
                    if (rml < mb) {
                        size_t orow = (MODE == 1) ? (size_t)(seg + ms + rml)
                                                  : (size_t)perm[seg + ms + rml];
                        if (ST32) out32[orow * N + gcol] = v;
                        if (ST16) out16[orow * N + gcol] = f2bf(v);
                    }
                }
            }
        }
    }
}

// ---------- flash attention (swapped QK^T), qkv bf16 [8192,2304] -> ctx bf16 [8192,768]
__global__ __launch_bounds__(256, 4) void attn_kernel(
    const u16* __restrict__ qkv, u16* __restrict__ ctx)
{
    __shared__ __attribute__((aligned(16))) u16 Ks[64 * 64];
    __shared__ __attribute__((aligned(16))) u16 Vs[64 * 68];
    int tid = threadIdx.x;
    int wv = tid >> 6, ln = tid & 63;
    int lr = ln & 15, hi = ln >> 4;
    int bh = blockIdx.y;
    int b = bh / HH, h = bh % HH;
    int q0 = blockIdx.x * 64 + wv * 16;
    size_t qrow = (size_t)(b * SEQ + q0 + lr);

    bf16x8 qf[2];
    {
        const u16* qp = qkv + qrow * 2304 + h * 64 + hi * 8;
        qf[0] = *(const bf16x8*)qp;
        qf[1] = *(const bf16x8*)(qp + 32);
    }
    f32x4 o[4];
    #pragma unroll
    for (int i = 0; i < 4; ++i) o[i] = f32x4{0.f, 0.f, 0.f, 0.f};
    float m_run = -INFINITY, l_run = 0.f;

    const size_t kbase = (size_t)b * SEQ * 2304 + 768 + h * 64;
    const size_t vbase = (size_t)b * SEQ * 2304 + 1536 + h * 64;

    for (int kt = 0; kt < SEQ / 64; ++kt) {
        int key0 = kt * 64;
        // stage K with XOR-swizzled source (row&7)<<4 bytes == (r&7)*8 elems
        #pragma unroll
        for (int i = 0; i < 2; ++i) {
            int r = (wv * 2 + i) * 8 + (ln >> 3);
            int csrc = ((ln & 7) * 8) ^ ((r & 7) * 8);
            gload_lds16(qkv + kbase + (size_t)(key0 + r) * 2304 + csrc,
                        &Ks[(wv * 2 + i) * 512]);
        }
        // stage V transposed: Vs[d][key], stride 68
        {
            int r = tid >> 2;
            int cb = (tid & 3) * 16;
            const u16* src = qkv + vbase + (size_t)(key0 + r) * 2304 + cb;
            u16 vals[16];
            *(uint4*)(vals)     = *(const uint4*)(const void*)(src);
            *(uint4*)(vals + 8) = *(const uint4*)(const void*)(src + 8);
            #pragma unroll
            for (int j = 0; j < 16; ++j) Vs[(cb + j) * 68 + r] = vals[j];
        }
        __syncthreads();

        // S^T = K * Q^T  (lane holds 16 scores, all for q = lane&15)
        f32x4 sf[4];
        #pragma unroll
        for (int f = 0; f < 4; ++f) {
            int key = f * 16 + lr;
            int sw = (key & 7) * 8;
            bf16x8 klo = *(const bf16x8*)&Ks[key * 64 + ((hi * 8) ^ sw)];
            bf16x8 khi = *(const bf16x8*)&Ks[key * 64 + ((32 + hi * 8) ^ sw)];
            f32x4 s = f32x4{0.f, 0.f, 0.f, 0.f};
            s = mfma16(klo, qf[0], s);
            s = mfma16(khi, qf[1], s);
            sf[f] = s;
        }

        float tmax = -INFINITY;
        #pragma unroll
        for (int f = 0; f < 4; ++f)
            #pragma unroll
            for (int i = 0; i < 4; ++i) {
                sf[f][i] *= 0.125f;          // 1/sqrt(64)
                tmax = fmaxf(tmax, sf[f][i]);
            }
        tmax = fmaxf(tmax, __shfl_xor(tmax, 16));
        tmax = fmaxf(tmax, __shfl_xor(tmax, 32));
        float m_new = fmaxf(m_run, tmax);
        float corr = exp2f((m_run - m_new) * LOG2E);
        float p[4][4];
        float psum = 0.f;
        #pragma unroll
        for (int f = 0; f < 4; ++f)
            #pragma unroll
            for (int i = 0; i < 4; ++i) {
                p[f][i] = exp2f((sf[f][i] - m_new) * LOG2E);
                psum += p[f][i];
            }
        psum += __shfl_xor(psum, 16);
        psum += __shfl_xor(psum, 32);
        l_run = l_run * corr + psum;
        m_run = m_new;
        #pragma unroll
        for (int dg = 0; dg < 4; ++dg) {
            o[dg][0] *= corr; o[dg][1] *= corr; o[dg][2] *= corr; o[dg][3] *= corr;
        }

        // O^T += V^T * P^T with shared k-bijection m(hi,i)=4hi+(i&3)+16(i>>2)
        #pragma unroll
        for (int kf = 0; kf < 2; ++kf) {
            union { bf16x8 v; u16 s[8]; } pb;
            pb.s[0] = f2bf(p[2 * kf][0]);     pb.s[1] = f2bf(p[2 * kf][1]);
            pb.s[2] = f2bf(p[2 * kf][2]);     pb.s[3] = f2bf(p[2 * kf][3]);
            pb.s[4] = f2bf(p[2 * kf + 1][0]); pb.s[5] = f2bf(p[2 * kf + 1][1]);
            pb.s[6] = f2bf(p[2 * kf + 1][2]); pb.s[7] = f2bf(p[2 * kf + 1][3]);
            #pragma unroll
            for (int dg = 0; dg < 4; ++dg) {
                int d = dg * 16 + lr;
                const u16* vp = &Vs[d * 68 + kf * 32 + hi * 4];
                union { bf16x8 v; uint2 u[2]; } va;
                va.u[0] = *(const uint2*)(const void*)(vp);
                va.u[1] = *(const uint2*)(const void*)(vp + 16);
                o[dg] = mfma16(va.v, pb.v, o[dg]);
            }
        }
        __syncthreads();
    }

    float inv = 1.f / l_run;
    #pragma unroll
    for (int dg = 0; dg < 4; ++dg) {
        uint2 pk;
        pk.x = (unsigned)f2bf(o[dg][0] * inv) | ((unsigned)f2bf(o[dg][1] * inv) << 16);
        pk.y = (unsigned)f2bf(o[dg][2] * inv) | ((unsigned)f2bf(o[dg][3] * inv) << 16);
        *(uint2*)(void*)&ctx[qrow * DM + h * 64 + dg * 16 + hi * 4] = pk;
    }
}

// ---------- way classifier: logits = out @ wcls + bcls ----------
__global__ __launch_bounds__(256) void cls_kernel(
    const float* __restrict__ outm, const float* __restrict__ wcls,
    const float* __restrict__ bcls, float* __restrict__ dst)
{
    int row = blockIdx.x, t = threadIdx.x;
    const float* xr = outm + (size_t)row * DM;
    float a0 = 0, a1 = 0, a2 = 0, a3 = 0;
    for (int j = t; j < DM; j += 256) {
        float xv = xr[j];
        float4 wv4 = *(const float4*)(const void*)(wcls + (size_t)j * 4);
        a0 += xv * wv4.x; a1 += xv * wv4.y; a2 += xv * wv4.z; a3 += xv * wv4.w;
    }
    #pragma unroll
    for (int k = 1; k < 64; k <<= 1) {
        a0 += __shfl_xor(a0, k); a1 += __shfl_xor(a1, k);
        a2 += __shfl_xor(a2, k); a3 += __shfl_xor(a3, k);
    }
    __shared__ float red[4][4];
    if ((t & 63) == 0) {
        int wid = t >> 6;
        red[wid][0] = a0; red[wid][1] = a1; red[wid][2] = a2; red[wid][3] = a3;
    }
    __syncthreads();
    if (t < 4)
        dst[(size_t)row * 4 + t] =
            red[0][t] + red[1][t] + red[2][t] + red[3][t] + bcls[t];
}

// ---------- launch ----------
extern "C" void kernel_launch(void* const* d_in, const int* in_sizes, int n_in,
                              void* d_out, int out_size, void* d_ws, size_t ws_size,
                              hipStream_t stream) {
    const float* x      = (const float*)d_in[0];
    const int*   wl     = (const int*)d_in[1];        // int inputs are int32
    const float* ln_g   = (const float*)d_in[2];
    const float* ln_b   = (const float*)d_in[3];
    const float* wq     = (const float*)d_in[4];
    const float* bq     = (const float*)d_in[5];
    const float* wk     = (const float*)d_in[6];
    const float* bk     = (const float*)d_in[7];
    const float* wvv    = (const float*)d_in[8];
    const float* bv     = (const float*)d_in[9];
    const float* wo     = (const float*)d_in[10];
    const float* bo     = (const float*)d_in[11];
    const float* wcls   = (const float*)d_in[12];
    const float* bcls   = (const float*)d_in[13];
    const float* w1     = (const float*)d_in[14];
    const float* b1     = (const float*)d_in[15];
    const float* w2     = (const float*)d_in[16];
    const float* b2     = (const float*)d_in[17];
    float* out = (float*)d_out;

    char* ws = (char*)d_ws;
    u16*   xn    = (u16*)  (ws + 0);            // 12,582,912 B
    u16*   qkv   = (u16*)  (ws + 12582912);     // 37,748,736 B
    u16*   hbuf  = (u16*)  (ws + 0);            // reuse xn+qkv (50,331,648 B)
    u16*   ctx   = (u16*)  (ws + 50331648);     // 12,582,912
    u16*   outb  = (u16*)  (ws + 62914560);     // 12,582,912
    u16*   wqkvt = (u16*)  (ws + 75497472);     // 3,538,944
    u16*   wot   = (u16*)  (ws + 79036416);     // 1,179,648
    u16*   w1t   = (u16*)  (ws + 80216064);     // 18,874,368
    u16*   w2t   = (u16*)  (ws + 99090432);     // 18,874,368
    float* bqkv  = (float*)(ws + 117964800);    // 9,216
    int*   perm  = (int*)  (ws + 117974016);    // 32,768
    int*   eoff  = (int*)  (ws + 118006784);    // 32
    int4*  fmap  = (int4*) (ws + 118006816);    // 1,088
    float* outf  = out;                          // f32 'out' lives in d_out ffn
                                                 // region; cls reads it BEFORE
                                                 // FFN2 scatter-overwrites it.

    route_kernel<<<1, 256, 0, stream>>>(wl, perm, eoff, fmap);
    concat_bias_kernel<<<9, 256, 0, stream>>>(bq, bk, bv, bqkv);
    dim3 tb(32, 8);
    transpose_bf16<<<dim3(24, 24, 1), tb, 0, stream>>>(wq,  wqkvt,             768, 768);
    transpose_bf16<<<dim3(24, 24, 1), tb, 0, stream>>>(wk,  wqkvt + 768 * 768, 768, 768);
    transpose_bf16<<<dim3(24, 24, 1), tb, 0, stream>>>(wvv, wqkvt + 2 * 768 * 768, 768, 768);
    transpose_bf16<<<dim3(24, 24, 1), tb, 0, stream>>>(wo,  wot, 768, 768);
    transpose_bf16<<<dim3(96, 24, 4), tb, 0, stream>>>(w1,  w1t, 768, 3072);
    transpose_bf16<<<dim3(24, 96, 4), tb, 0, stream>>>(w2,  w2t, 3072, 768);
    ln_kernel<<<MB_TOK, 256, 0, stream>>>(x, ln_g, ln_b, xn);

    // QKV: [8192,768] x [768,2304]
    gemm_bt_kernel<0, false, false, false, true><<<64 * 18, 256, 0, stream>>>(
        xn, wqkvt, bqkv, nullptr, nullptr, qkv, MB_TOK, 2304, 768, 18, nullptr, nullptr);

    attn_kernel<<<dim3(32, 48), 256, 0, stream>>>(qkv, ctx);

    // WO + residual: out = ctx@wo + bo + x  (f32 into d_out ffn region + bf16 copy)
    gemm_bt_kernel<0, false, true, true, true><<<64 * 6, 256, 0, stream>>>(
        ctx, wot, bo, x, outf, outb, MB_TOK, 768, 768, 6, nullptr, nullptr);

    cls_kernel<<<MB_TOK, 256, 0, stream>>>(outf, wcls, bcls, out + (size_t)MB_TOK * DM);

    // FFN1: gathered rows, relu -> h
    gemm_bt_kernel<1, true, false, false, true><<<68 * 24, 256, 0, stream>>>(
        outb, w1t, b1, nullptr, nullptr, hbuf, MB_TOK, DFF, 768, 24, perm, fmap);

    // FFN2: h -> scatter into d_out (overwrites outf region entirely)
    gemm_bt_kernel<2, false, false, true, false><<<68 * 6, 256, 0, stream>>>(
        hbuf, w2t, b2, nullptr, out, nullptr, MB_TOK, 768, DFF, 6, perm, fmap);
}

// Round 3
// 410.451 us; speedup vs baseline: 1.0621x; 1.0621x over previous
//
#include <hip/hip_runtime.h>
#include <cstdint>

typedef unsigned short u16;
typedef float f32x4 __attribute__((ext_vector_type(4)));
typedef __bf16 bf16x8 __attribute__((ext_vector_type(8)));

#define LOG2E 1.44269504088896340736f

// ---------- helpers ----------
__device__ __forceinline__ u16 f2bf(float f) {
    union { float f; unsigned u; } v; v.f = f;
    unsigned r = v.u + 0x7fffu + ((v.u >> 16) & 1u);   // RNE
    return (u16)(r >> 16);
}

__device__ __forceinline__ unsigned cvt_pk_bf16(float lo, float hi) {
    unsigned r;
    asm("v_cvt_pk_bf16_f32 %0, %1, %2" : "=v"(r) : "v"(lo), "v"(hi));
    return r;
}

__device__ __forceinline__ f32x4 mfma16(bf16x8 a, bf16x8 b, f32x4 c) {
    return __builtin_amdgcn_mfma_f32_16x16x32_bf16(a, b, c, 0, 0, 0);
}

__device__ __forceinline__ void gload_lds16(const void* g, void* l) {
    __builtin_amdgcn_global_load_lds(
        (__attribute__((address_space(1))) unsigned int*)(g),
        (__attribute__((address_space(3))) unsigned int*)(l),
        16, 0, 0);
}

// ---------- constants ----------
#define MB_TOK 8192      // B*S
#define DM 768
#define HH 12
#define DHD 64
#define NWAY 4
#define DFF 3072
#define SEQ 2048
#define NBATCH 4

// ---------- LayerNorm: x f32 [8192,768] -> xn bf16 ----------
__global__ __launch_bounds__(256) void ln_kernel(
    const float* __restrict__ x, const float* __restrict__ g,
    const float* __restrict__ bb, u16* __restrict__ xn)
{
    int row = blockIdx.x, t = threadIdx.x;
    const float* xr = x + (size_t)row * DM;
    float v0 = xr[t], v1 = xr[t + 256], v2 = xr[t + 512];
    float s = v0 + v1 + v2;
    __shared__ float red[4];
    #pragma unroll
    for (int k = 1; k < 64; k <<= 1) s += __shfl_xor(s, k);
    if ((t & 63) == 0) red[t >> 6] = s;
    __syncthreads();
    float mu = (red[0] + red[1] + red[2] + red[3]) * (1.f / 768.f);
    float d0 = v0 - mu, d1 = v1 - mu, d2 = v2 - mu;
    float q = d0 * d0 + d1 * d1 + d2 * d2;
    #pragma unroll
    for (int k = 1; k < 64; k <<= 1) q += __shfl_xor(q, k);
    __syncthreads();
    if ((t & 63) == 0) red[t >> 6] = q;
    __syncthreads();
    float var = (red[0] + red[1] + red[2] + red[3]) * (1.f / 768.f);
    float rs = rsqrtf(var + 1e-6f);
    u16* xo = xn + (size_t)row * DM;
    xo[t]       = f2bf(d0 * rs * g[t]       + bb[t]);
    xo[t + 256] = f2bf(d1 * rs * g[t + 256] + bb[t + 256]);
    xo[t + 512] = f2bf(d2 * rs * g[t + 512] + bb[t + 512]);
}

// ---------- transpose+convert: src f32 [K][N] -> dst bf16 [N][K], batched ----------
__global__ __launch_bounds__(256) void transpose_bf16(
    const float* __restrict__ src, u16* __restrict__ dst, int K, int N)
{
    __shared__ float tl[32][33];
    size_t bofs = (size_t)blockIdx.z * K * N;
    src += bofs; dst += bofs;
    int n0 = blockIdx.x * 32, k0 = blockIdx.y * 32;
    int tx = threadIdx.x, ty = threadIdx.y;
    #pragma unroll
    for (int j = 0; j < 4; ++j)
        tl[ty + j * 8][tx] = src[(size_t)(k0 + ty + j * 8) * N + n0 + tx];
    __syncthreads();
    #pragma unroll
    for (int j = 0; j < 4; ++j)
        dst[(size_t)(n0 + ty + j * 8) * K + k0 + tx] = f2bf(tl[tx][ty + j * 8]);
}

// ---------- V transpose: qkv bf16 V-cols -> vT[bh][d][key] ----------
__global__ __launch_bounds__(256) void vT_kernel(
    const u16* __restrict__ qkv, u16* __restrict__ vT)
{
    __shared__ u16 tl[32][33];
    int bh = blockIdx.z;
    int b = bh / HH, h = bh % HH;
    int key0 = blockIdx.x * 32;
    int d0 = blockIdx.y * 32;
    int tx = threadIdx.x, ty = threadIdx.y;
    const u16* src = qkv + ((size_t)b * SEQ + key0) * 2304 + 1536 + h * 64 + d0;
    #pragma unroll
    for (int j = 0; j < 4; ++j)
        tl[ty + j * 8][tx] = src[(size_t)(ty + j * 8) * 2304 + tx];
    __syncthreads();
    u16* dst = vT + ((size_t)bh * 64 + d0) * SEQ + key0;
    #pragma unroll
    for (int j = 0; j < 4; ++j)
        dst[(size_t)(ty + j * 8) * SEQ + tx] = tl[tx][ty + j * 8];
}

// ---------- bias concat q|k|v ----------
__global__ void concat_bias_kernel(const float* bq, const float* bk,
                                   const float* bv, float* bqkv)
{
    int i = blockIdx.x * 256 + threadIdx.x;
    if (i < 2304) bqkv[i] = i < 768 ? bq[i] : (i < 1536 ? bk[i - 768] : bv[i - 1536]);
}

// ---------- routing: counts, offsets, perm, tile map ----------
__global__ void route_kernel(const int* __restrict__ wl,
                             int* __restrict__ perm, int* __restrict__ eoff,
                             int4* __restrict__ fmap)
{
    __shared__ int cnt[4], cur[4], off[5];
    int tid = threadIdx.x;
    if (tid < 4) cnt[tid] = 0;
    __syncthreads();
    for (int t = tid; t < MB_TOK; t += 256) atomicAdd(&cnt[wl[t] & 3], 1);
    __syncthreads();
    if (tid == 0) {
        off[0] = 0;
        for (int e = 0; e < 4; ++e) off[e + 1] = off[e] + cnt[e];
        int idx = 0;
        for (int e = 0; e < 4; ++e)
            for (int s = 0; s < cnt[e]; s += 128)
                fmap[idx++] = make_int4(e, off[e], s, cnt[e] - s);
        for (; idx < 68; ++idx) fmap[idx] = make_int4(-1, 0, 0, 0);
        for (int e = 0; e < 5; ++e) eoff[e] = off[e];
        for (int e = 0; e < 4; ++e) cur[e] = off[e];
    }
    __syncthreads();
    for (int t = tid; t < MB_TOK; t += 256) {
        int e = wl[t] & 3;
        int pos = atomicAdd(&cur[e], 1);
        perm[pos] = t;
    }
}

// ---------- GEMM: C[M,N] = A[M,K](bf16) * Bt[N,K](bf16)^T + bias ----------
// MODE 0: dense. MODE 1: A rows via perm (FFN1). MODE 2: C rows via perm (FFN2).
template<int MODE, bool RELU, bool RES, bool ST32, bool ST16>
__global__ __launch_bounds__(256, 2) void gemm_bt_kernel(
    const u16* __restrict__ A, const u16* __restrict__ Bt,
    const float* __restrict__ bias, const float* __restrict__ res,
    float* __restrict__ out32, u16* __restrict__ out16,
    int M, int N, int K, int ntn,
    const int* __restrict__ perm, const int4* __restrict__ fmap)
{
    __shared__ __attribute__((aligned(16))) u16 As[128 * 32];
    __shared__ __attribute__((aligned(16))) u16 Bs[128 * 32];
    int tid = threadIdx.x;
    int wv = tid >> 6, ln = tid & 63;
    int bt = blockIdx.x / ntn;
    int tn = (blockIdx.x % ntn) * 128;

    int seg = 0, ms = 0, mb = 128, tm = 0;
    if (MODE != 0) {
        int4 ent = fmap[bt];
        if (ent.x < 0) return;
        seg = ent.y; ms = ent.z; mb = ent.w; if (mb > 128) mb = 128;
        Bt += (size_t)ent.x * N * K;
        bias += ent.x * N;
    } else {
        tm = bt * 128;
    }

    f32x4 acc[4][4];
    #pragma unroll
    for (int i = 0; i < 4; ++i)
        #pragma unroll
        for (int j = 0; j < 4; ++j) acc[i][j] = f32x4{0.f, 0.f, 0.f, 0.f};

    int wr = wv >> 1, wc = wv & 1;
    int lr = ln & 15, hi = ln >> 4;
    int nk = K / 32;

    for (int kk = 0; kk < nk; ++kk) {
        int k0 = kk * 32;
        #pragma unroll
        for (int i = 0; i < 2; ++i) {          // stage A (2 x 1KB per wave)
            int r = (wv * 2 + i) * 16 + (ln >> 2);
            int am = r < mb ? r : (mb - 1);
            size_t arow;
            if (MODE == 1)      arow = (size_t)perm[seg + ms + am];
            else if (MODE == 2) arow = (size_t)(seg + ms + am);
            else                arow = (size_t)(tm + r);
            gload_lds16(A + arow * K + k0 + (ln & 3) * 8, &As[(wv * 2 + i) * 512]);
        }
        #pragma unroll
        for (int i = 0; i < 2; ++i) {          // stage B
            int r = (wv * 2 + i) * 16 + (ln >> 2);
            gload_lds16(Bt + (size_t)(tn + r) * K + k0 + (ln & 3) * 8,
                        &Bs[(wv * 2 + i) * 512]);
        }
        __syncthreads();
        bf16x8 a[4], b[4];
        #pragma unroll
        for (int m = 0; m < 4; ++m)
            a[m] = *(const bf16x8*)&As[(wr * 64 + m * 16 + lr) * 32 + hi * 8];
        #pragma unroll
        for (int n = 0; n < 4; ++n)
            b[n] = *(const bf16x8*)&Bs[(wc * 64 + n * 16 + lr) * 32 + hi * 8];
        #pragma unroll
        for (int m = 0; m < 4; ++m)
            #pragma unroll
            for (int n = 0; n < 4; ++n)
                acc[m][n] = mfma16(a[m], b[n], acc[m][n]);
        __syncthreads();
    }

    // epilogue: C/D layout col=lane&15, row=(lane>>4)*4+i
    #pragma unroll
    for (int m = 0; m < 4; ++m) {
        int rb = wr * 64 + m * 16 + hi * 4;
        #pragma unroll
        for (int n = 0; n < 4; ++n) {
            int gcol = tn + wc * 64 + n * 16 + lr;
            float bvv = bias[gcol];
            #pragma unroll
            for (int i = 0; i < 4; ++i) {
                int rml = rb + i;
                float v = acc[m][n][i] + bvv;
                if (RELU) v = v > 0.f ? v : 0.f;
                if (MODE == 0) {
                    size_t grow = (size_t)(tm + rml);
                    if (RES) v += res[grow * N + gcol];
                    if (ST32) out32[grow * N + gcol] = v;
                    if (ST16) out16[grow * N + gcol] = f2bf(v);
                } else {
                    if (rml < mb) {
                        size_t orow = (MODE == 1) ? (size_t)(seg + ms + rml)
                                                  : (size_t)perm[seg + ms + rml];
                        if (ST32) out32[orow * N + gcol] = v;
                        if (ST16) out16[orow * N + gcol] = f2bf(v);
                    }
                }
            }
        }
    }
}

// ---------- flash attention (swapped QK^T), K from qkv, V from vT ----------
__global__ __launch_bounds__(256, 4) void attn_kernel(
    const u16* __restrict__ qkv, const u16* __restrict__ vT,
    u16* __restrict__ ctx)
{
    __shared__ __attribute__((aligned(16))) u16 Ks[64 * 64];
    __shared__ __attribute__((aligned(16))) u16 Vs[64 * 64];
    int tid = threadIdx.x;
    int wv = tid >> 6, ln = tid & 63;
    int lr = ln & 15, hi = ln >> 4;
    int bh = blockIdx.y;
    int b = bh / HH, h = bh % HH;
    int q0 = blockIdx.x * 64 + wv * 16;
    size_t qrow = (size_t)(b * SEQ + q0 + lr);
    const float C = 0.125f * LOG2E;          // fold 1/sqrt(64) into exp2 arg

    bf16x8 qf[2];
    {
        const u16* qp = qkv + qrow * 2304 + h * 64 + hi * 8;
        qf[0] = *(const bf16x8*)qp;
        qf[1] = *(const bf16x8*)(qp + 32);
    }
    f32x4 o[4];
    #pragma unroll
    for (int i = 0; i < 4; ++i) o[i] = f32x4{0.f, 0.f, 0.f, 0.f};
    float m_run = -INFINITY, l_run = 0.f;

    const size_t kbase = (size_t)b * SEQ * 2304 + 768 + h * 64;
    const u16* vtb = vT + (size_t)bh * 64 * SEQ;
    int scol = (ln & 7) * 8;

    for (int kt = 0; kt < SEQ / 64; ++kt) {
        int key0 = kt * 64;
        // stage K rows (from qkv) and V^T rows (from vT), XOR-swizzled source
        #pragma unroll
        for (int i = 0; i < 2; ++i) {
            int r = wv * 16 + i * 8 + (ln >> 3);
            int csrc = scol ^ ((r & 7) * 8);
            gload_lds16(qkv + kbase + (size_t)(key0 + r) * 2304 + csrc,
                        &Ks[(wv * 2 + i) * 512]);
            gload_lds16(vtb + (size_t)r * SEQ + key0 + csrc,
                        &Vs[(wv * 2 + i) * 512]);
        }
        __syncthreads();

        // S^T = K * Q^T  (lane holds 16 raw scores for q = lane&15)
        f32x4 sf[4];
        #pragma unroll
        for (int f = 0; f < 4; ++f) {
            int key = f * 16 + lr;
            int sw = (key & 7) * 8;
            bf16x8 klo = *(const bf16x8*)&Ks[key * 64 + ((hi * 8) ^ sw)];
            bf16x8 khi = *(const bf16x8*)&Ks[key * 64 + ((32 + hi * 8) ^ sw)];
            f32x4 s = f32x4{0.f, 0.f, 0.f, 0.f};
            s = mfma16(klo, qf[0], s);
            s = mfma16(khi, qf[1], s);
            sf[f] = s;
        }

        float tmax = sf[0][0];
        #pragma unroll
        for (int f = 0; f < 4; ++f)
            #pragma unroll
            for (int i = 0; i < 4; ++i) tmax = fmaxf(tmax, sf[f][i]);
        tmax = fmaxf(tmax, __shfl_xor(tmax, 16));
        tmax = fmaxf(tmax, __shfl_xor(tmax, 32));

        // defer-max (T13): rescale only when tile max exceeds m_run by >8 nats
        if (!__all(tmax - m_run <= 64.f)) {
            float m_new = fmaxf(m_run, tmax);
            float corr = exp2f((m_run - m_new) * C);
            l_run *= corr;
            #pragma unroll
            for (int dg = 0; dg < 4; ++dg) {
                o[dg][0] *= corr; o[dg][1] *= corr;
                o[dg][2] *= corr; o[dg][3] *= corr;
            }
            m_run = m_new;
        }

        float c2 = -m_run * C;
        float p[4][4];
        float psum = 0.f;
        #pragma unroll
        for (int f = 0; f < 4; ++f)
            #pragma unroll
            for (int i = 0; i < 4; ++i) {
                p[f][i] = exp2f(fmaf(sf[f][i], C, c2));
                psum += p[f][i];
            }
        psum += __shfl_xor(psum, 16);
        psum += __shfl_xor(psum, 32);
        l_run += psum;

        // O^T += V^T * P^T with shared k-slot map m(hi,j)=4hi+(j&3)+16(j>>2)
        #pragma unroll
        for (int kf = 0; kf < 2; ++kf) {
            union { bf16x8 v; unsigned u[4]; } pb;
            pb.u[0] = cvt_pk_bf16(p[2 * kf][0], p[2 * kf][1]);
            pb.u[1] = cvt_pk_bf16(p[2 * kf][2], p[2 * kf][3]);
            pb.u[2] = cvt_pk_bf16(p[2 * kf + 1][0], p[2 * kf + 1][1]);
            pb.u[3] = cvt_pk_bf16(p[2 * kf + 1][2], p[2 * kf + 1][3]);
            #pragma unroll
            for (int dg = 0; dg < 4; ++dg) {
                int d = dg * 16 + lr;
                int sw = (d & 7) * 16;                  // byte swizzle
                const char* vb = (const char*)Vs + d * 128;
                union { bf16x8 v; uint2 u[2]; } va;
                va.u[0] = *(const uint2*)(const void*)(vb + ((kf * 64 + hi * 8) ^ sw));
                va.u[1] = *(const uint2*)(const void*)(vb + ((kf * 64 + hi * 8 + 32) ^ sw));
                o[dg] = mfma16(va.v, pb.v, o[dg]);
            }
        }
        __syncthreads();
    }

    float inv = 1.f / l_run;
    #pragma unroll
    for (int dg = 0; dg < 4; ++dg) {
        uint2 pk;
        pk.x = cvt_pk_bf16(o[dg][0] * inv, o[dg][1] * inv);
        pk.y = cvt_pk_bf16(o[dg][2] * inv, o[dg][3] * inv);
        *(uint2*)(void*)&ctx[qrow * DM + h * 64 + dg * 16 + hi * 4] = pk;
    }
}

// ---------- way classifier: logits = out @ wcls + bcls ----------
__global__ __launch_bounds__(256) void cls_kernel(
    const float* __restrict__ outm, const float* __restrict__ wcls,
    const float* __restrict__ bcls, float* __restrict__ dst)
{
    int row = blockIdx.x, t = threadIdx.x;
    const float* xr = outm + (size_t)row * DM;
    float a0 = 0, a1 = 0, a2 = 0, a3 = 0;
    for (int j = t; j < DM; j += 256) {
        float xv = xr[j];
        float4 wv4 = *(const float4*)(const void*)(wcls + (size_t)j * 4);
        a0 += xv * wv4.x; a1 += xv * wv4.y; a2 += xv * wv4.z; a3 += xv * wv4.w;
    }
    #pragma unroll
    for (int k = 1; k < 64; k <<= 1) {
        a0 += __shfl_xor(a0, k); a1 += __shfl_xor(a1, k);
        a2 += __shfl_xor(a2, k); a3 += __shfl_xor(a3, k);
    }
    __shared__ float red[4][4];
    if ((t & 63) == 0) {
        int wid = t >> 6;
        red[wid][0] = a0; red[wid][1] = a1; red[wid][2] = a2; red[wid][3] = a3;
    }
    __syncthreads();
    if (t < 4)
        dst[(size_t)row * 4 + t] =
            red[0][t] + red[1][t] + red[2][t] + red[3][t] + bcls[t];
}

// ---------- launch ----------
extern "C" void kernel_launch(void* const* d_in, const int* in_sizes, int n_in,
                              void* d_out, int out_size, void* d_ws, size_t ws_size,
                              hipStream_t stream) {
    const float* x      = (const float*)d_in[0];
    const int*   wl     = (const int*)d_in[1];        // int inputs are int32
    const float* ln_g   = (const float*)d_in[2];
    const float* ln_b   = (const float*)d_in[3];
    const float* wq     = (const float*)d_in[4];
    const float* bq     = (const float*)d_in[5];
    const float* wk     = (const float*)d_in[6];
    const float* bk     = (const float*)d_in[7];
    const float* wvv    = (const float*)d_in[8];
    const float* bv     = (const float*)d_in[9];
    const float* wo     = (const float*)d_in[10];
    const float* bo     = (const float*)d_in[11];
    const float* wcls   = (const float*)d_in[12];
    const float* bcls   = (const float*)d_in[13];
    const float* w1     = (const float*)d_in[14];
    const float* b1     = (const float*)d_in[15];
    const float* w2     = (const float*)d_in[16];
    const float* b2     = (const float*)d_in[17];
    float* out = (float*)d_out;

    char* ws = (char*)d_ws;
    u16*   xn    = (u16*)  (ws + 0);            // 12,582,912 B
    u16*   qkv   = (u16*)  (ws + 12582912);     // 37,748,736 B
    u16*   hbuf  = (u16*)  (ws + 0);            // reuse xn+qkv (50,331,648 B)
    u16*   ctx   = (u16*)  (ws + 50331648);     // 12,582,912
    u16*   outb  = (u16*)  (ws + 62914560);     // 12,582,912
    u16*   wqkvt = (u16*)  (ws + 75497472);     // 3,538,944
    u16*   wot   = (u16*)  (ws + 79036416);     // 1,179,648
    u16*   w1t   = (u16*)  (ws + 80216064);     // 18,874,368
    u16*   w2t   = (u16*)  (ws + 99090432);     // 18,874,368
    float* bqkv  = (float*)(ws + 117964800);    // 9,216
    int*   perm  = (int*)  (ws + 117974016);    // 32,768
    int*   eoff  = (int*)  (ws + 118006784);    // 32
    int4*  fmap  = (int4*) (ws + 118006816);    // 1,088
    u16*   vT    = (u16*)  (ws + 118008064);    // 12,582,912 (aligned 16)
    float* outf  = out;                          // f32 'out' lives in d_out ffn
                                                 // region; cls reads it BEFORE
                                                 // FFN2 scatter-overwrites it.

    route_kernel<<<1, 256, 0, stream>>>(wl, perm, eoff, fmap);
    concat_bias_kernel<<<9, 256, 0, stream>>>(bq, bk, bv, bqkv);
    dim3 tb(32, 8);
    transpose_bf16<<<dim3(24, 24, 1), tb, 0, stream>>>(wq,  wqkvt,             768, 768);
    transpose_bf16<<<dim3(24, 24, 1), tb, 0, stream>>>(wk,  wqkvt + 768 * 768, 768, 768);
    transpose_bf16<<<dim3(24, 24, 1), tb, 0, stream>>>(wvv, wqkvt + 2 * 768 * 768, 768, 768);
    transpose_bf16<<<dim3(24, 24, 1), tb, 0, stream>>>(wo,  wot, 768, 768);
    transpose_bf16<<<dim3(96, 24, 4), tb, 0, stream>>>(w1,  w1t, 768, 3072);
    transpose_bf16<<<dim3(24, 96, 4), tb, 0, stream>>>(w2,  w2t, 3072, 768);
    ln_kernel<<<MB_TOK, 256, 0, stream>>>(x, ln_g, ln_b, xn);

    // QKV: [8192,768] x [768,2304]
    gemm_bt_kernel<0, false, false, false, true><<<64 * 18, 256, 0, stream>>>(
        xn, wqkvt, bqkv, nullptr, nullptr, qkv, MB_TOK, 2304, 768, 18, nullptr, nullptr);

    // V transpose for attention PV operand
    vT_kernel<<<dim3(64, 2, 48), tb, 0, stream>>>(qkv, vT);

    attn_kernel<<<dim3(32, 48), 256, 0, stream>>>(qkv, vT, ctx);

    // WO + residual: out = ctx@wo + bo + x  (f32 into d_out ffn region + bf16 copy)
    gemm_bt_kernel<0, false, true, true, true><<<64 * 6, 256, 0, stream>>>(
        ctx, wot, bo, x, outf, outb, MB_TOK, 768, 768, 6, nullptr, nullptr);

    cls_kernel<<<MB_TOK, 256, 0, stream>>>(outf, wcls, bcls, out + (size_t)MB_TOK * DM);

    // FFN1: gathered rows, relu -> h
    gemm_bt_kernel<1, true, false, false, true><<<68 * 24, 256, 0, stream>>>(
        outb, w1t, b1, nullptr, nullptr, hbuf, MB_TOK, DFF, 768, 24, perm, fmap);

    // FFN2: h -> scatter into d_out (overwrites outf region entirely)
    gemm_bt_kernel<2, false, false, true, false><<<68 * 6, 256, 0, stream>>>(
        hbuf, w2t, b2, nullptr, out, nullptr, MB_TOK, 768, DFF, 6, perm, fmap);
}

// Round 4
// 376.523 us; speedup vs baseline: 1.1578x; 1.0901x over previous
//
#include <hip/hip_runtime.h>
#include <cstdint>

typedef unsigned short u16;
typedef float f32x4 __attribute__((ext_vector_type(4)));
typedef float f32x16 __attribute__((ext_vector_type(16)));
typedef __bf16 bf16x8 __attribute__((ext_vector_type(8)));

#define LOG2E 1.44269504088896340736f

// ---------- helpers ----------
__device__ __forceinline__ u16 f2bf(float f) {
    union { float f; unsigned u; } v; v.f = f;
    unsigned r = v.u + 0x7fffu + ((v.u >> 16) & 1u);   // RNE
    return (u16)(r >> 16);
}

__device__ __forceinline__ unsigned cvt_pk_bf16(float lo, float hi) {
    unsigned r;
    asm("v_cvt_pk_bf16_f32 %0, %1, %2" : "=v"(r) : "v"(lo), "v"(hi));
    return r;
}

__device__ __forceinline__ float exp2_hw(float x) {
    float r;
    asm("v_exp_f32 %0, %1" : "=v"(r) : "v"(x));
    return r;
}

__device__ __forceinline__ f32x4 mfma16(bf16x8 a, bf16x8 b, f32x4 c) {
    return __builtin_amdgcn_mfma_f32_16x16x32_bf16(a, b, c, 0, 0, 0);
}

__device__ __forceinline__ f32x16 mfma32(bf16x8 a, bf16x8 b, f32x16 c) {
    return __builtin_amdgcn_mfma_f32_32x32x16_bf16(a, b, c, 0, 0, 0);
}

__device__ __forceinline__ void gload_lds16(const void* g, void* l) {
    __builtin_amdgcn_global_load_lds(
        (__attribute__((address_space(1))) unsigned int*)(g),
        (__attribute__((address_space(3))) unsigned int*)(l),
        16, 0, 0);
}

// ---------- constants ----------
#define MB_TOK 8192      // B*S
#define DM 768
#define HH 12
#define DHD 64
#define NWAY 4
#define DFF 3072
#define SEQ 2048
#define NBATCH 4

// ---------- LayerNorm: x f32 [8192,768] -> xn bf16 ----------
__global__ __launch_bounds__(256) void ln_kernel(
    const float* __restrict__ x, const float* __restrict__ g,
    const float* __restrict__ bb, u16* __restrict__ xn)
{
    int row = blockIdx.x, t = threadIdx.x;
    const float* xr = x + (size_t)row * DM;
    float v0 = xr[t], v1 = xr[t + 256], v2 = xr[t + 512];
    float s = v0 + v1 + v2;
    __shared__ float red[4];
    #pragma unroll
    for (int k = 1; k < 64; k <<= 1) s += __shfl_xor(s, k);
    if ((t & 63) == 0) red[t >> 6] = s;
    __syncthreads();
    float mu = (red[0] + red[1] + red[2] + red[3]) * (1.f / 768.f);
    float d0 = v0 - mu, d1 = v1 - mu, d2 = v2 - mu;
    float q = d0 * d0 + d1 * d1 + d2 * d2;
    #pragma unroll
    for (int k = 1; k < 64; k <<= 1) q += __shfl_xor(q, k);
    __syncthreads();
    if ((t & 63) == 0) red[t >> 6] = q;
    __syncthreads();
    float var = (red[0] + red[1] + red[2] + red[3]) * (1.f / 768.f);
    float rs = rsqrtf(var + 1e-6f);
    u16* xo = xn + (size_t)row * DM;
    xo[t]       = f2bf(d0 * rs * g[t]       + bb[t]);
    xo[t + 256] = f2bf(d1 * rs * g[t + 256] + bb[t + 256]);
    xo[t + 512] = f2bf(d2 * rs * g[t + 512] + bb[t + 512]);
}

// ---------- transpose+convert: src f32 [K][N] -> dst bf16 [N][K], batched ----------
__global__ __launch_bounds__(256) void transpose_bf16(
    const float* __restrict__ src, u16* __restrict__ dst, int K, int N)
{
    __shared__ float tl[32][33];
    size_t bofs = (size_t)blockIdx.z * K * N;
    src += bofs; dst += bofs;
    int n0 = blockIdx.x * 32, k0 = blockIdx.y * 32;
    int tx = threadIdx.x, ty = threadIdx.y;
    #pragma unroll
    for (int j = 0; j < 4; ++j)
        tl[ty + j * 8][tx] = src[(size_t)(k0 + ty + j * 8) * N + n0 + tx];
    __syncthreads();
    #pragma unroll
    for (int j = 0; j < 4; ++j)
        dst[(size_t)(n0 + ty + j * 8) * K + k0 + tx] = f2bf(tl[tx][ty + j * 8]);
}

// ---------- V transpose: qkv bf16 V-cols -> vT[bh][d][key] ----------
__global__ __launch_bounds__(256) void vT_kernel(
    const u16* __restrict__ qkv, u16* __restrict__ vT)
{
    __shared__ u16 tl[32][33];
    int bh = blockIdx.z;
    int b = bh / HH, h = bh % HH;
    int key0 = blockIdx.x * 32;
    int d0 = blockIdx.y * 32;
    int tx = threadIdx.x, ty = threadIdx.y;
    const u16* src = qkv + ((size_t)b * SEQ + key0) * 2304 + 1536 + h * 64 + d0;
    #pragma unroll
    for (int j = 0; j < 4; ++j)
        tl[ty + j * 8][tx] = src[(size_t)(ty + j * 8) * 2304 + tx];
    __syncthreads();
    u16* dst = vT + ((size_t)bh * 64 + d0) * SEQ + key0;
    #pragma unroll
    for (int j = 0; j < 4; ++j)
        dst[(size_t)(ty + j * 8) * SEQ + tx] = tl[tx][ty + j * 8];
}

// ---------- bias concat q|k|v ----------
__global__ void concat_bias_kernel(const float* bq, const float* bk,
                                   const float* bv, float* bqkv)
{
    int i = blockIdx.x * 256 + threadIdx.x;
    if (i < 2304) bqkv[i] = i < 768 ? bq[i] : (i < 1536 ? bk[i - 768] : bv[i - 1536]);
}

// ---------- routing: counts, offsets, perm, tile map ----------
__global__ void route_kernel(const int* __restrict__ wl,
                             int* __restrict__ perm, int* __restrict__ eoff,
                             int4* __restrict__ fmap)
{
    __shared__ int cnt[4], cur[4], off[5];
    int tid = threadIdx.x;
    if (tid < 4) cnt[tid] = 0;
    __syncthreads();
    for (int t = tid; t < MB_TOK; t += 256) atomicAdd(&cnt[wl[t] & 3], 1);
    __syncthreads();
    if (tid == 0) {
        off[0] = 0;
        for (int e = 0; e < 4; ++e) off[e + 1] = off[e] + cnt[e];
        int idx = 0;
        for (int e = 0; e < 4; ++e)
            for (int s = 0; s < cnt[e]; s += 128)
                fmap[idx++] = make_int4(e, off[e], s, cnt[e] - s);
        for (; idx < 68; ++idx) fmap[idx] = make_int4(-1, 0, 0, 0);
        for (int e = 0; e < 5; ++e) eoff[e] = off[e];
        for (int e = 0; e < 4; ++e) cur[e] = off[e];
    }
    __syncthreads();
    for (int t = tid; t < MB_TOK; t += 256) {
        int e = wl[t] & 3;
        int pos = atomicAdd(&cur[e], 1);
        perm[pos] = t;
    }
}

// ---------- GEMM: C[M,N] = A[M,K](bf16) * Bt[N,K](bf16)^T + bias ----------
// MODE 0: dense. MODE 1: A rows via perm (FFN1). MODE 2: C rows via perm (FFN2).
template<int MODE, bool RELU, bool RES, bool ST32, bool ST16>
__global__ __launch_bounds__(256, 2) void gemm_bt_kernel(
    const u16* __restrict__ A, const u16* __restrict__ Bt,
    const float* __restrict__ bias, const float* __restrict__ res,
    float* __restrict__ out32, u16* __restrict__ out16,
    int M, int N, int K, int ntn,
    const int* __restrict__ perm, const int4* __restrict__ fmap)
{
    __shared__ __attribute__((aligned(16))) u16 As[128 * 32];
    __shared__ __attribute__((aligned(16))) u16 Bs[128 * 32];
    int tid = threadIdx.x;
    int wv = tid >> 6, ln = tid & 63;
    int bt = blockIdx.x / ntn;
    int tn = (blockIdx.x % ntn) * 128;

    int seg = 0, ms = 0, mb = 128, tm = 0;
    if (MODE != 0) {
        int4 ent = fmap[bt];
        if (ent.x < 0) return;
        seg = ent.y; ms = ent.z; mb = ent.w; if (mb > 128) mb = 128;
        Bt += (size_t)ent.x * N * K;
        bias += ent.x * N;
    } else {
        tm = bt * 128;
    }

    f32x4 acc[4][4];
    #pragma unroll
    for (int i = 0; i < 4; ++i)
        #pragma unroll
        for (int j = 0; j < 4; ++j) acc[i][j] = f32x4{0.f, 0.f, 0.f, 0.f};

    int wr = wv >> 1, wc = wv & 1;
    int lr = ln & 15, hi = ln >> 4;
    int nk = K / 32;

    for (int kk = 0; kk < nk; ++kk) {
        int k0 = kk * 32;
        #pragma unroll
        for (int i = 0; i < 2; ++i) {          // stage A (2 x 1KB per wave)
            int r = (wv * 2 + i) * 16 + (ln >> 2);
            int am = r < mb ? r : (mb - 1);
            size_t arow;
            if (MODE == 1)      arow = (size_t)perm[seg + ms + am];
            else if (MODE == 2) arow = (size_t)(seg + ms + am);
            else                arow = (size_t)(tm + r);
            gload_lds16(A + arow * K + k0 + (ln & 3) * 8, &As[(wv * 2 + i) * 512]);
        }
        #pragma unroll
        for (int i = 0; i < 2; ++i) {          // stage B
            int r = (wv * 2 + i) * 16 + (ln >> 2);
            gload_lds16(Bt + (size_t)(tn + r) * K + k0 + (ln & 3) * 8,
                        &Bs[(wv * 2 + i) * 512]);
        }
        __syncthreads();
        bf16x8 a[4], b[4];
        #pragma unroll
        for (int m = 0; m < 4; ++m)
            a[m] = *(const bf16x8*)&As[(wr * 64 + m * 16 + lr) * 32 + hi * 8];
        #pragma unroll
        for (int n = 0; n < 4; ++n)
            b[n] = *(const bf16x8*)&Bs[(wc * 64 + n * 16 + lr) * 32 + hi * 8];
        #pragma unroll
        for (int m = 0; m < 4; ++m)
            #pragma unroll
            for (int n = 0; n < 4; ++n)
                acc[m][n] = mfma16(a[m], b[n], acc[m][n]);
        __syncthreads();
    }

    // epilogue: C/D layout col=lane&15, row=(lane>>4)*4+i
    #pragma unroll
    for (int m = 0; m < 4; ++m) {
        int rb = wr * 64 + m * 16 + hi * 4;
        #pragma unroll
        for (int n = 0; n < 4; ++n) {
            int gcol = tn + wc * 64 + n * 16 + lr;
            float bvv = bias[gcol];
            #pragma unroll
            for (int i = 0; i < 4; ++i) {
                int rml = rb + i;
                float v = acc[m][n][i] + bvv;
                if (RELU) v = v > 0.f ? v : 0.f;
                if (MODE == 0) {
                    size_t grow = (size_t)(tm + rml);
                    if (RES) v += res[grow * N + gcol];
                    if (ST32) out32[grow * N + gcol] = v;
                    if (ST16) out16[grow * N + gcol] = f2bf(v);
                } else {
                    if (rml < mb) {
                        size_t orow = (MODE == 1) ? (size_t)(seg + ms + rml)
                                                  : (size_t)perm[seg + ms + rml];
                        if (ST32) out32[orow * N + gcol] = v;
                        if (ST16) out16[orow * N + gcol] = f2bf(v);
                    }
                }
            }
        }
    }
}

// ---------- flash attention: 32x32 MFMA, 32 q/wave, double-buffered K/V ----------
// S^T = K·Q^T per 32-key block; lane holds 32 scores of ONE q row (q = ln&31).
// acc C/D map: row(key) = (reg&3)+8*(reg>>2)+4*hi, col(q) = ln&31  [m74/m101]
__global__ __launch_bounds__(256, 4) void attn_kernel(
    const u16* __restrict__ qkv, const u16* __restrict__ vT,
    u16* __restrict__ ctx)
{
    __shared__ __attribute__((aligned(16))) u16 Ks[2][4096];
    __shared__ __attribute__((aligned(16))) u16 Vs[2][4096];
    int tid = threadIdx.x;
    int wv = tid >> 6, ln = tid & 63;
    int qv = ln & 31, hi = ln >> 5;
    int bid = blockIdx.x;
    // XCD-chunked mapping: each XCD owns 6 consecutive bh values
    int bh = (bid & 7) * 6 + ((bid >> 3) % 6);
    int qt = (bid >> 3) / 6;
    int b = bh / HH, h = bh % HH;
    int q0 = qt * 128 + wv * 32;
    size_t qrowb = (size_t)(b * SEQ + q0);
    const float C = 0.125f * LOG2E;

    // Q B-frags (col=q=ln&31, k = ds*16 + hi*8 + j)
    bf16x8 qf[4];
    {
        const u16* qp = qkv + (qrowb + qv) * 2304 + h * 64 + hi * 8;
        #pragma unroll
        for (int ds = 0; ds < 4; ++ds) qf[ds] = *(const bf16x8*)(qp + ds * 16);
    }

    // staging pointers (pre-swizzled source, linear LDS dest)
    int csrc = 8 * ((ln & 7) ^ (ln >> 3));
    const size_t kbase = (size_t)b * SEQ * 2304 + 768 + h * 64;
    const u16* vtb = vT + (size_t)bh * 64 * SEQ;
    const u16* kp0 = qkv + kbase + (size_t)(wv * 16 + (ln >> 3)) * 2304 + csrc;
    const u16* kp1 = kp0 + (size_t)8 * 2304;
    const u16* vp0 = vtb + (size_t)(wv * 16 + (ln >> 3)) * SEQ + csrc;
    const u16* vp1 = vp0 + (size_t)8 * SEQ;

#define ATTN_STAGE(bf_, t_) do {                                          \
    gload_lds16(kp0 + (size_t)(t_) * 64 * 2304, &Ks[bf_][(wv * 2) * 512]);\
    gload_lds16(kp1 + (size_t)(t_) * 64 * 2304, &Ks[bf_][(wv * 2 + 1) * 512]);\
    gload_lds16(vp0 + (size_t)(t_) * 64, &Vs[bf_][(wv * 2) * 512]);       \
    gload_lds16(vp1 + (size_t)(t_) * 64, &Vs[bf_][(wv * 2 + 1) * 512]);   \
} while (0)

    f32x16 oacc[2];
    #pragma unroll
    for (int i = 0; i < 2; ++i)
        #pragma unroll
        for (int r = 0; r < 16; ++r) oacc[i][r] = 0.f;
    float m_run = -INFINITY, l_run = 0.f;
    int ksw = (qv & 7) * 8;

    ATTN_STAGE(0, 0);

    for (int kt = 0; kt < SEQ / 64; ++kt) {
        int bf = kt & 1;
        __syncthreads();                      // buf[bf] ready (vmcnt drained)
        if (kt + 1 < SEQ / 64) ATTN_STAGE(bf ^ 1, kt + 1);

        // ---- QK^T: two 32-key blocks ----
        f32x16 s0, s1;
        #pragma unroll
        for (int r = 0; r < 16; ++r) { s0[r] = 0.f; s1[r] = 0.f; }
        #pragma unroll
        for (int ds = 0; ds < 4; ++ds) {
            bf16x8 ka0 = *(const bf16x8*)&Ks[bf][qv * 64 + ((ds * 16 + hi * 8) ^ ksw)];
            bf16x8 ka1 = *(const bf16x8*)&Ks[bf][(32 + qv) * 64 + ((ds * 16 + hi * 8) ^ ksw)];
            s0 = mfma32(ka0, qf[ds], s0);
            s1 = mfma32(ka1, qf[ds], s1);
        }

        // ---- softmax (row-local; only one shfl for cross-half max) ----
        float tmax = s0[0];
        #pragma unroll
        for (int r = 1; r < 16; ++r) tmax = fmaxf(tmax, s0[r]);
        #pragma unroll
        for (int r = 0; r < 16; ++r) tmax = fmaxf(tmax, s1[r]);
        tmax = fmaxf(tmax, __shfl_xor(tmax, 32));

        if (!__all(tmax - m_run <= 64.f)) {   // defer-max (T13), 8 nats
            float m_new = fmaxf(m_run, tmax);
            float corr = exp2_hw((m_run - m_new) * C);
            l_run *= corr;
            #pragma unroll
            for (int i = 0; i < 2; ++i)
                #pragma unroll
                for (int r = 0; r < 16; ++r) oacc[i][r] *= corr;
            m_run = m_new;
        }
        float c2 = -m_run * C;
        float psum = 0.f;
        #pragma unroll
        for (int r = 0; r < 16; ++r) {
            s0[r] = exp2_hw(fmaf(s0[r], C, c2)); psum += s0[r];
            s1[r] = exp2_hw(fmaf(s1[r], C, c2)); psum += s1[r];
        }
        l_run += psum;                        // per-half partial; combined at end

        // ---- PV: O^T += V^T · P^T ----
        #pragma unroll
        for (int kb = 0; kb < 2; ++kb) {
            #pragma unroll
            for (int hc = 0; hc < 2; ++hc) {
                // build P^T B-frag (keys kb*32+hc*16+hi*8+{0..7}, col=q)
                const f32x16& sv = kb ? s1 : s0;
                unsigned x0 = cvt_pk_bf16(sv[8 * hc + 0], sv[8 * hc + 1]);
                unsigned x1 = cvt_pk_bf16(sv[8 * hc + 2], sv[8 * hc + 3]);
                unsigned x2 = cvt_pk_bf16(sv[8 * hc + 4], sv[8 * hc + 5]);
                unsigned x3 = cvt_pk_bf16(sv[8 * hc + 6], sv[8 * hc + 7]);
                unsigned t0 = hi ? x0 : x2, t1 = hi ? x1 : x3;
                unsigned r0 = (unsigned)__shfl_xor((int)t0, 32);
                unsigned r1 = (unsigned)__shfl_xor((int)t1, 32);
                union { bf16x8 v; unsigned u[4]; } pf;
                pf.u[0] = hi ? r0 : x0; pf.u[1] = hi ? r1 : x1;
                pf.u[2] = hi ? x2 : r0; pf.u[3] = hi ? x3 : r1;
                int kc = (kb * 32 + hc * 16 + hi * 8) ^ ksw;
                #pragma unroll
                for (int dblk = 0; dblk < 2; ++dblk) {
                    bf16x8 va = *(const bf16x8*)&Vs[bf][(dblk * 32 + qv) * 64 + kc];
                    oacc[dblk] = mfma32(va, pf.v, oacc[dblk]);
                }
            }
        }
    }
#undef ATTN_STAGE

    // ---- epilogue: normalize, transpose via per-wave LDS, coalesced store ----
    float l_tot = l_run + __shfl_xor(l_run, 32);
    float inv = 1.f / l_tot;

    __syncthreads();                          // all tile reads done; reuse Ks
    u16* eb = &Ks[0][0] + wv * 2048;          // per-wave 32q x 64d region
    #pragma unroll
    for (int dblk = 0; dblk < 2; ++dblk)
        #pragma unroll
        for (int r = 0; r < 16; r += 2) {
            int d = dblk * 32 + (r & 3) + 8 * (r >> 2) + 4 * hi;
            unsigned pk = cvt_pk_bf16(oacc[dblk][r] * inv, oacc[dblk][r + 1] * inv);
            *(unsigned*)&eb[qv * 64 + (d ^ ((qv & 7) * 8))] = pk;
        }
    __syncthreads();
    {
        u16* ctr = ctx + (qrowb + qv) * DM + h * 64 + hi * 32;
        #pragma unroll
        for (int g = 0; g < 4; ++g) {
            bf16x8 vv = *(const bf16x8*)&eb[qv * 64 + ((hi * 32 + g * 8) ^ ((qv & 7) * 8))];
            *(bf16x8*)(ctr + g * 8) = vv;
        }
    }
}

// ---------- way classifier: logits = out @ wcls + bcls ----------
__global__ __launch_bounds__(256) void cls_kernel(
    const float* __restrict__ outm, const float* __restrict__ wcls,
    const float* __restrict__ bcls, float* __restrict__ dst)
{
    int row = blockIdx.x, t = threadIdx.x;
    const float* xr = outm + (size_t)row * DM;
    float a0 = 0, a1 = 0, a2 = 0, a3 = 0;
    for (int j = t; j < DM; j += 256) {
        float xv = xr[j];
        float4 wv4 = *(const float4*)(const void*)(wcls + (size_t)j * 4);
        a0 += xv * wv4.x; a1 += xv * wv4.y; a2 += xv * wv4.z; a3 += xv * wv4.w;
    }
    #pragma unroll
    for (int k = 1; k < 64; k <<= 1) {
        a0 += __shfl_xor(a0, k); a1 += __shfl_xor(a1, k);
        a2 += __shfl_xor(a2, k); a3 += __shfl_xor(a3, k);
    }
    __shared__ float red[4][4];
    if ((t & 63) == 0) {
        int wid = t >> 6;
        red[wid][0] = a0; red[wid][1] = a1; red[wid][2] = a2; red[wid][3] = a3;
    }
    __syncthreads();
    if (t < 4)
        dst[(size_t)row * 4 + t] =
            red[0][t] + red[1][t] + red[2][t] + red[3][t] + bcls[t];
}

// ---------- launch ----------
extern "C" void kernel_launch(void* const* d_in, const int* in_sizes, int n_in,
                              void* d_out, int out_size, void* d_ws, size_t ws_size,
                              hipStream_t stream) {
    const float* x      = (const float*)d_in[0];
    const int*   wl     = (const int*)d_in[1];        // int inputs are int32
    const float* ln_g   = (const float*)d_in[2];
    const float* ln_b   = (const float*)d_in[3];
    const float* wq     = (const float*)d_in[4];
    const float* bq     = (const float*)d_in[5];
    const float* wk     = (const float*)d_in[6];
    const float* bk     = (const float*)d_in[7];
    const float* wvv    = (const float*)d_in[8];
    const float* bv     = (const float*)d_in[9];
    const float* wo     = (const float*)d_in[10];
    const float* bo     = (const float*)d_in[11];
    const float* wcls   = (const float*)d_in[12];
    const float* bcls   = (const float*)d_in[13];
    const float* w1     = (const float*)d_in[14];
    const float* b1     = (const float*)d_in[15];
    const float* w2     = (const float*)d_in[16];
    const float* b2     = (const float*)d_in[17];
    float* out = (float*)d_out;

    char* ws = (char*)d_ws;
    u16*   xn    = (u16*)  (ws + 0);            // 12,582,912 B
    u16*   qkv   = (u16*)  (ws + 12582912);     // 37,748,736 B
    u16*   hbuf  = (u16*)  (ws + 0);            // reuse xn+qkv (50,331,648 B)
    u16*   ctx   = (u16*)  (ws + 50331648);     // 12,582,912
    u16*   outb  = (u16*)  (ws + 62914560);     // 12,582,912
    u16*   wqkvt = (u16*)  (ws + 75497472);     // 3,538,944
    u16*   wot   = (u16*)  (ws + 79036416);     // 1,179,648
    u16*   w1t   = (u16*)  (ws + 80216064);     // 18,874,368
    u16*   w2t   = (u16*)  (ws + 99090432);     // 18,874,368
    float* bqkv  = (float*)(ws + 117964800);    // 9,216
    int*   perm  = (int*)  (ws + 117974016);    // 32,768
    int*   eoff  = (int*)  (ws + 118006784);    // 32
    int4*  fmap  = (int4*) (ws + 118006816);    // 1,088
    u16*   vT    = (u16*)  (ws + 118008064);    // 12,582,912 (aligned 16)
    float* outf  = out;                          // f32 'out' lives in d_out ffn
                                                 // region; cls reads it BEFORE
                                                 // FFN2 scatter-overwrites it.

    route_kernel<<<1, 256, 0, stream>>>(wl, perm, eoff, fmap);
    concat_bias_kernel<<<9, 256, 0, stream>>>(bq, bk, bv, bqkv);
    dim3 tb(32, 8);
    transpose_bf16<<<dim3(24, 24, 1), tb, 0, stream>>>(wq,  wqkvt,             768, 768);
    transpose_bf16<<<dim3(24, 24, 1), tb, 0, stream>>>(wk,  wqkvt + 768 * 768, 768, 768);
    transpose_bf16<<<dim3(24, 24, 1), tb, 0, stream>>>(wvv, wqkvt + 2 * 768 * 768, 768, 768);
    transpose_bf16<<<dim3(24, 24, 1), tb, 0, stream>>>(wo,  wot, 768, 768);
    transpose_bf16<<<dim3(96, 24, 4), tb, 0, stream>>>(w1,  w1t, 768, 3072);
    transpose_bf16<<<dim3(24, 96, 4), tb, 0, stream>>>(w2,  w2t, 3072, 768);
    ln_kernel<<<MB_TOK, 256, 0, stream>>>(x, ln_g, ln_b, xn);

    // QKV: [8192,768] x [768,2304]
    gemm_bt_kernel<0, false, false, false, true><<<64 * 18, 256, 0, stream>>>(
        xn, wqkvt, bqkv, nullptr, nullptr, qkv, MB_TOK, 2304, 768, 18, nullptr, nullptr);

    // V transpose for attention PV operand
    vT_kernel<<<dim3(64, 2, 48), tb, 0, stream>>>(qkv, vT);

    attn_kernel<<<768, 256, 0, stream>>>(qkv, vT, ctx);

    // WO + residual: out = ctx@wo + bo + x  (f32 into d_out ffn region + bf16 copy)
    gemm_bt_kernel<0, false, true, true, true><<<64 * 6, 256, 0, stream>>>(
        ctx, wot, bo, x, outf, outb, MB_TOK, 768, 768, 6, nullptr, nullptr);

    cls_kernel<<<MB_TOK, 256, 0, stream>>>(outf, wcls, bcls, out + (size_t)MB_TOK * DM);

    // FFN1: gathered rows, relu -> h
    gemm_bt_kernel<1, true, false, false, true><<<68 * 24, 256, 0, stream>>>(
        outb, w1t, b1, nullptr, nullptr, hbuf, MB_TOK, DFF, 768, 24, perm, fmap);

    // FFN2: h -> scatter into d_out (overwrites outf region entirely)
    gemm_bt_kernel<2, false, false, true, false><<<68 * 6, 256, 0, stream>>>(
        hbuf, w2t, b2, nullptr, out, nullptr, MB_TOK, 768, DFF, 6, perm, fmap);
}

// Round 5
// 373.068 us; speedup vs baseline: 1.1686x; 1.0093x over previous
//
#include <hip/hip_runtime.h>
#include <cstdint>

typedef unsigned short u16;
typedef float f32x4 __attribute__((ext_vector_type(4)));
typedef float f32x16 __attribute__((ext_vector_type(16)));
typedef __bf16 bf16x8 __attribute__((ext_vector_type(8)));

#define LOG2E 1.44269504088896340736f

// ---------- helpers ----------
__device__ __forceinline__ u16 f2bf(float f) {
    union { float f; unsigned u; } v; v.f = f;
    unsigned r = v.u + 0x7fffu + ((v.u >> 16) & 1u);   // RNE
    return (u16)(r >> 16);
}

__device__ __forceinline__ unsigned cvt_pk_bf16(float lo, float hi) {
    unsigned r;
    asm("v_cvt_pk_bf16_f32 %0, %1, %2" : "=v"(r) : "v"(lo), "v"(hi));
    return r;
}

__device__ __forceinline__ float exp2_hw(float x) {
    float r;
    asm("v_exp_f32 %0, %1" : "=v"(r) : "v"(x));
    return r;
}

__device__ __forceinline__ f32x4 mfma16(bf16x8 a, bf16x8 b, f32x4 c) {
    return __builtin_amdgcn_mfma_f32_16x16x32_bf16(a, b, c, 0, 0, 0);
}

__device__ __forceinline__ f32x16 mfma32(bf16x8 a, bf16x8 b, f32x16 c) {
    return __builtin_amdgcn_mfma_f32_32x32x16_bf16(a, b, c, 0, 0, 0);
}

__device__ __forceinline__ void gload_lds16(const void* g, void* l) {
    __builtin_amdgcn_global_load_lds(
        (__attribute__((address_space(1))) unsigned int*)(g),
        (__attribute__((address_space(3))) unsigned int*)(l),
        16, 0, 0);
}

// ---------- constants ----------
#define MB_TOK 8192      // B*S
#define DM 768
#define HH 12
#define DHD 64
#define NWAY 4
#define DFF 3072
#define SEQ 2048
#define NBATCH 4

// ---------- LayerNorm: x f32 [8192,768] -> xn bf16 ----------
__global__ __launch_bounds__(256) void ln_kernel(
    const float* __restrict__ x, const float* __restrict__ g,
    const float* __restrict__ bb, u16* __restrict__ xn)
{
    int row = blockIdx.x, t = threadIdx.x;
    const float* xr = x + (size_t)row * DM;
    float v0 = xr[t], v1 = xr[t + 256], v2 = xr[t + 512];
    float s = v0 + v1 + v2;
    __shared__ float red[4];
    #pragma unroll
    for (int k = 1; k < 64; k <<= 1) s += __shfl_xor(s, k);
    if ((t & 63) == 0) red[t >> 6] = s;
    __syncthreads();
    float mu = (red[0] + red[1] + red[2] + red[3]) * (1.f / 768.f);
    float d0 = v0 - mu, d1 = v1 - mu, d2 = v2 - mu;
    float q = d0 * d0 + d1 * d1 + d2 * d2;
    #pragma unroll
    for (int k = 1; k < 64; k <<= 1) q += __shfl_xor(q, k);
    __syncthreads();
    if ((t & 63) == 0) red[t >> 6] = q;
    __syncthreads();
    float var = (red[0] + red[1] + red[2] + red[3]) * (1.f / 768.f);
    float rs = rsqrtf(var + 1e-6f);
    u16* xo = xn + (size_t)row * DM;
    xo[t]       = f2bf(d0 * rs * g[t]       + bb[t]);
    xo[t + 256] = f2bf(d1 * rs * g[t + 256] + bb[t + 256]);
    xo[t + 512] = f2bf(d2 * rs * g[t + 512] + bb[t + 512]);
}

// ---------- transpose+convert: src f32 [K][N] -> dst bf16 [N][K], batched ----------
__global__ __launch_bounds__(256) void transpose_bf16(
    const float* __restrict__ src, u16* __restrict__ dst, int K, int N)
{
    __shared__ float tl[32][33];
    size_t bofs = (size_t)blockIdx.z * K * N;
    src += bofs; dst += bofs;
    int n0 = blockIdx.x * 32, k0 = blockIdx.y * 32;
    int tx = threadIdx.x, ty = threadIdx.y;
    #pragma unroll
    for (int j = 0; j < 4; ++j)
        tl[ty + j * 8][tx] = src[(size_t)(k0 + ty + j * 8) * N + n0 + tx];
    __syncthreads();
    #pragma unroll
    for (int j = 0; j < 4; ++j)
        dst[(size_t)(n0 + ty + j * 8) * K + k0 + tx] = f2bf(tl[tx][ty + j * 8]);
}

// ---------- V transpose: qkv bf16 V-cols -> vT[bh][d][key] ----------
__global__ __launch_bounds__(256) void vT_kernel(
    const u16* __restrict__ qkv, u16* __restrict__ vT)
{
    __shared__ u16 tl[32][33];
    int bh = blockIdx.z;
    int b = bh / HH, h = bh % HH;
    int key0 = blockIdx.x * 32;
    int d0 = blockIdx.y * 32;
    int tx = threadIdx.x, ty = threadIdx.y;
    const u16* src = qkv + ((size_t)b * SEQ + key0) * 2304 + 1536 + h * 64 + d0;
    #pragma unroll
    for (int j = 0; j < 4; ++j)
        tl[ty + j * 8][tx] = src[(size_t)(ty + j * 8) * 2304 + tx];
    __syncthreads();
    u16* dst = vT + ((size_t)bh * 64 + d0) * SEQ + key0;
    #pragma unroll
    for (int j = 0; j < 4; ++j)
        dst[(size_t)(ty + j * 8) * SEQ + tx] = tl[tx][ty + j * 8];
}

// ---------- bias concat q|k|v ----------
__global__ void concat_bias_kernel(const float* bq, const float* bk,
                                   const float* bv, float* bqkv)
{
    int i = blockIdx.x * 256 + threadIdx.x;
    if (i < 2304) bqkv[i] = i < 768 ? bq[i] : (i < 1536 ? bk[i - 768] : bv[i - 1536]);
}

// ---------- routing: counts, offsets, perm, tile map ----------
__global__ void route_kernel(const int* __restrict__ wl,
                             int* __restrict__ perm, int* __restrict__ eoff,
                             int4* __restrict__ fmap)
{
    __shared__ int cnt[4], cur[4], off[5];
    int tid = threadIdx.x;
    if (tid < 4) cnt[tid] = 0;
    __syncthreads();
    for (int t = tid; t < MB_TOK; t += 256) atomicAdd(&cnt[wl[t] & 3], 1);
    __syncthreads();
    if (tid == 0) {
        off[0] = 0;
        for (int e = 0; e < 4; ++e) off[e + 1] = off[e] + cnt[e];
        int idx = 0;
        for (int e = 0; e < 4; ++e)
            for (int s = 0; s < cnt[e]; s += 128)
                fmap[idx++] = make_int4(e, off[e], s, cnt[e] - s);
        for (; idx < 72; ++idx) fmap[idx] = make_int4(-1, 0, 0, 0);
        for (int e = 0; e < 5; ++e) eoff[e] = off[e];
        for (int e = 0; e < 4; ++e) cur[e] = off[e];
    }
    __syncthreads();
    for (int t = tid; t < MB_TOK; t += 256) {
        int e = wl[t] & 3;
        int pos = atomicAdd(&cur[e], 1);
        perm[pos] = t;
    }
}

// ---------- GEMM: C[M,N] = A[M,K](bf16) * Bt[N,K](bf16)^T + bias ----------
// MODE 0: dense. MODE 1: A rows via perm (FFN1). MODE 2: C rows via perm (FFN2).
// Double-buffered LDS (T3-minimal 2-phase) + XCD-chunked block mapping:
// xcd = blockIdx&7 owns a contiguous bt range; tn varies fastest within it,
// so all N-tiles sharing an A-tile hit the same XCD's L2 back-to-back.
template<int MODE, bool RELU, bool RES, bool ST32, bool ST16>
__global__ __launch_bounds__(256, 3) void gemm_bt_kernel(
    const u16* __restrict__ A, const u16* __restrict__ Bt,
    const float* __restrict__ bias, const float* __restrict__ res,
    float* __restrict__ out32, u16* __restrict__ out16,
    int nbt, int N, int K, int ntn,
    const int* __restrict__ perm, const int4* __restrict__ fmap)
{
    __shared__ __attribute__((aligned(16))) u16 As[2][4096];
    __shared__ __attribute__((aligned(16))) u16 Bs[2][4096];
    int tid = threadIdx.x;
    int wv = tid >> 6, ln = tid & 63;
    int bpx = gridDim.x / (ntn << 3);          // bt tiles per XCD
    int jj = blockIdx.x >> 3;
    int bt = (blockIdx.x & 7) * bpx + jj / ntn;
    int tn = (jj % ntn) * 128;
    if (bt >= nbt) return;

    int seg = 0, ms = 0, mb = 128, tm = 0;
    if (MODE != 0) {
        int4 ent = fmap[bt];
        if (ent.x < 0) return;
        seg = ent.y; ms = ent.z; mb = ent.w; if (mb > 128) mb = 128;
        Bt += (size_t)ent.x * N * K;
        bias += ent.x * N;
    } else {
        tm = bt * 128;
    }

    f32x4 acc[4][4];
    #pragma unroll
    for (int i = 0; i < 4; ++i)
        #pragma unroll
        for (int j = 0; j < 4; ++j) acc[i][j] = f32x4{0.f, 0.f, 0.f, 0.f};

    int wr = wv >> 1, wc = wv & 1;
    int lr = ln & 15, hi = ln >> 4;
    int nk = K / 32;

    // precompute per-thread staging source bases (row const across K-steps)
    const u16* asrc[2];
    const u16* bsrc[2];
    #pragma unroll
    for (int i = 0; i < 2; ++i) {
        int r = (wv * 2 + i) * 16 + (ln >> 2);
        int am = r < mb ? r : (mb - 1);
        size_t arow;
        if (MODE == 1)      arow = (size_t)perm[seg + ms + am];
        else if (MODE == 2) arow = (size_t)(seg + ms + am);
        else                arow = (size_t)(tm + r);
        asrc[i] = A + arow * K + (ln & 3) * 8;
        bsrc[i] = Bt + (size_t)(tn + r) * K + (ln & 3) * 8;
    }

#define GSTAGE(bf_, k0_) do {                                             \
    gload_lds16(asrc[0] + (k0_), &As[bf_][(wv * 2) * 512]);               \
    gload_lds16(asrc[1] + (k0_), &As[bf_][(wv * 2 + 1) * 512]);           \
    gload_lds16(bsrc[0] + (k0_), &Bs[bf_][(wv * 2) * 512]);               \
    gload_lds16(bsrc[1] + (k0_), &Bs[bf_][(wv * 2 + 1) * 512]);           \
} while (0)

    GSTAGE(0, 0);
    for (int kk = 0; kk < nk; ++kk) {
        int bf = kk & 1;
        __syncthreads();                       // drains vmcnt: buf[bf] ready
        if (kk + 1 < nk) GSTAGE(bf ^ 1, (kk + 1) * 32);
        bf16x8 a[4], b[4];
        #pragma unroll
        for (int m = 0; m < 4; ++m)
            a[m] = *(const bf16x8*)&As[bf][(wr * 64 + m * 16 + lr) * 32 + hi * 8];
        #pragma unroll
        for (int n = 0; n < 4; ++n)
            b[n] = *(const bf16x8*)&Bs[bf][(wc * 64 + n * 16 + lr) * 32 + hi * 8];
        #pragma unroll
        for (int m = 0; m < 4; ++m)
            #pragma unroll
            for (int n = 0; n < 4; ++n)
                acc[m][n] = mfma16(a[m], b[n], acc[m][n]);
    }
#undef GSTAGE

    // epilogue: C/D layout col=lane&15, row=(lane>>4)*4+i
    #pragma unroll
    for (int m = 0; m < 4; ++m) {
        int rb = wr * 64 + m * 16 + hi * 4;
        #pragma unroll
        for (int n = 0; n < 4; ++n) {
            int gcol = tn + wc * 64 + n * 16 + lr;
            float bvv = bias[gcol];
            #pragma unroll
            for (int i = 0; i < 4; ++i) {
                int rml = rb + i;
                float v = acc[m][n][i] + bvv;
                if (RELU) v = v > 0.f ? v : 0.f;
                if (MODE == 0) {
                    size_t grow = (size_t)(tm + rml);
                    if (RES) v += res[grow * N + gcol];
                    if (ST32) out32[grow * N + gcol] = v;
                    if (ST16) out16[grow * N + gcol] = f2bf(v);
                } else {
                    if (rml < mb) {
                        size_t orow = (MODE == 1) ? (size_t)(seg + ms + rml)
                                                  : (size_t)perm[seg + ms + rml];
                        if (ST32) out32[orow * N + gcol] = v;
                        if (ST16) out16[orow * N + gcol] = f2bf(v);
                    }
                }
            }
        }
    }
}

// ---------- flash attention: 32x32 MFMA, 32 q/wave, double-buffered K/V ----------
// S^T = K·Q^T per 32-key block; lane holds 32 scores of ONE q row (q = ln&31).
// acc C/D map: row(key) = (reg&3)+8*(reg>>2)+4*hi, col(q) = ln&31  [m74/m101]
__global__ __launch_bounds__(256, 4) void attn_kernel(
    const u16* __restrict__ qkv, const u16* __restrict__ vT,
    u16* __restrict__ ctx)
{
    __shared__ __attribute__((aligned(16))) u16 Ks[2][4096];
    __shared__ __attribute__((aligned(16))) u16 Vs[2][4096];
    int tid = threadIdx.x;
    int wv = tid >> 6, ln = tid & 63;
    int qv = ln & 31, hi = ln >> 5;
    int bid = blockIdx.x;
    // XCD-chunked mapping: each XCD owns 6 consecutive bh values
    int bh = (bid & 7) * 6 + ((bid >> 3) % 6);
    int qt = (bid >> 3) / 6;
    int b = bh / HH, h = bh % HH;
    int q0 = qt * 128 + wv * 32;
    size_t qrowb = (size_t)(b * SEQ + q0);
    const float C = 0.125f * LOG2E;

    // Q B-frags (col=q=ln&31, k = ds*16 + hi*8 + j)
    bf16x8 qf[4];
    {
        const u16* qp = qkv + (qrowb + qv) * 2304 + h * 64 + hi * 8;
        #pragma unroll
        for (int ds = 0; ds < 4; ++ds) qf[ds] = *(const bf16x8*)(qp + ds * 16);
    }

    // staging pointers (pre-swizzled source, linear LDS dest)
    int csrc = 8 * ((ln & 7) ^ (ln >> 3));
    const size_t kbase = (size_t)b * SEQ * 2304 + 768 + h * 64;
    const u16* vtb = vT + (size_t)bh * 64 * SEQ;
    const u16* kp0 = qkv + kbase + (size_t)(wv * 16 + (ln >> 3)) * 2304 + csrc;
    const u16* kp1 = kp0 + (size_t)8 * 2304;
    const u16* vp0 = vtb + (size_t)(wv * 16 + (ln >> 3)) * SEQ + csrc;
    const u16* vp1 = vp0 + (size_t)8 * SEQ;

#define ATTN_STAGE(bf_, t_) do {                                          \
    gload_lds16(kp0 + (size_t)(t_) * 64 * 2304, &Ks[bf_][(wv * 2) * 512]);\
    gload_lds16(kp1 + (size_t)(t_) * 64 * 2304, &Ks[bf_][(wv * 2 + 1) * 512]);\
    gload_lds16(vp0 + (size_t)(t_) * 64, &Vs[bf_][(wv * 2) * 512]);       \
    gload_lds16(vp1 + (size_t)(t_) * 64, &Vs[bf_][(wv * 2 + 1) * 512]);   \
} while (0)

    f32x16 oacc[2];
    #pragma unroll
    for (int i = 0; i < 2; ++i)
        #pragma unroll
        for (int r = 0; r < 16; ++r) oacc[i][r] = 0.f;
    float m_run = -INFINITY, l_run = 0.f;
    int ksw = (qv & 7) * 8;

    ATTN_STAGE(0, 0);

    for (int kt = 0; kt < SEQ / 64; ++kt) {
        int bf = kt & 1;
        __syncthreads();                      // buf[bf] ready (vmcnt drained)
        if (kt + 1 < SEQ / 64) ATTN_STAGE(bf ^ 1, kt + 1);

        // ---- QK^T: two 32-key blocks ----
        f32x16 s0, s1;
        #pragma unroll
        for (int r = 0; r < 16; ++r) { s0[r] = 0.f; s1[r] = 0.f; }
        #pragma unroll
        for (int ds = 0; ds < 4; ++ds) {
            bf16x8 ka0 = *(const bf16x8*)&Ks[bf][qv * 64 + ((ds * 16 + hi * 8) ^ ksw)];
            bf16x8 ka1 = *(const bf16x8*)&Ks[bf][(32 + qv) * 64 + ((ds * 16 + hi * 8) ^ ksw)];
            s0 = mfma32(ka0, qf[ds], s0);
            s1 = mfma32(ka1, qf[ds], s1);
        }

        // ---- softmax (row-local; only one shfl for cross-half max) ----
        float tmax = s0[0];
        #pragma unroll
        for (int r = 1; r < 16; ++r) tmax = fmaxf(tmax, s0[r]);
        #pragma unroll
        for (int r = 0; r < 16; ++r) tmax = fmaxf(tmax, s1[r]);
        tmax = fmaxf(tmax, __shfl_xor(tmax, 32));

        if (!__all(tmax - m_run <= 64.f)) {   // defer-max (T13), 8 nats
            float m_new = fmaxf(m_run, tmax);
            float corr = exp2_hw((m_run - m_new) * C);
            l_run *= corr;
            #pragma unroll
            for (int i = 0; i < 2; ++i)
                #pragma unroll
                for (int r = 0; r < 16; ++r) oacc[i][r] *= corr;
            m_run = m_new;
        }
        float c2 = -m_run * C;
        float psum = 0.f;
        #pragma unroll
        for (int r = 0; r < 16; ++r) {
            s0[r] = exp2_hw(fmaf(s0[r], C, c2)); psum += s0[r];
            s1[r] = exp2_hw(fmaf(s1[r], C, c2)); psum += s1[r];
        }
        l_run += psum;                        // per-half partial; combined at end

        // ---- PV: O^T += V^T · P^T ----
        #pragma unroll
        for (int kb = 0; kb < 2; ++kb) {
            #pragma unroll
            for (int hc = 0; hc < 2; ++hc) {
                // build P^T B-frag (keys kb*32+hc*16+hi*8+{0..7}, col=q)
                const f32x16& sv = kb ? s1 : s0;
                unsigned x0 = cvt_pk_bf16(sv[8 * hc + 0], sv[8 * hc + 1]);
                unsigned x1 = cvt_pk_bf16(sv[8 * hc + 2], sv[8 * hc + 3]);
                unsigned x2 = cvt_pk_bf16(sv[8 * hc + 4], sv[8 * hc + 5]);
                unsigned x3 = cvt_pk_bf16(sv[8 * hc + 6], sv[8 * hc + 7]);
                unsigned t0 = hi ? x0 : x2, t1 = hi ? x1 : x3;
                unsigned r0 = (unsigned)__shfl_xor((int)t0, 32);
                unsigned r1 = (unsigned)__shfl_xor((int)t1, 32);
                union { bf16x8 v; unsigned u[4]; } pf;
                pf.u[0] = hi ? r0 : x0; pf.u[1] = hi ? r1 : x1;
                pf.u[2] = hi ? x2 : r0; pf.u[3] = hi ? x3 : r1;
                int kc = (kb * 32 + hc * 16 + hi * 8) ^ ksw;
                #pragma unroll
                for (int dblk = 0; dblk < 2; ++dblk) {
                    bf16x8 va = *(const bf16x8*)&Vs[bf][(dblk * 32 + qv) * 64 + kc];
                    oacc[dblk] = mfma32(va, pf.v, oacc[dblk]);
                }
            }
        }
    }
#undef ATTN_STAGE

    // ---- epilogue: normalize, transpose via per-wave LDS, coalesced store ----
    float l_tot = l_run + __shfl_xor(l_run, 32);
    float inv = 1.f / l_tot;

    __syncthreads();                          // all tile reads done; reuse Ks
    u16* eb = &Ks[0][0] + wv * 2048;          // per-wave 32q x 64d region
    #pragma unroll
    for (int dblk = 0; dblk < 2; ++dblk)
        #pragma unroll
        for (int r = 0; r < 16; r += 2) {
            int d = dblk * 32 + (r & 3) + 8 * (r >> 2) + 4 * hi;
            unsigned pk = cvt_pk_bf16(oacc[dblk][r] * inv, oacc[dblk][r + 1] * inv);
            *(unsigned*)&eb[qv * 64 + (d ^ ((qv & 7) * 8))] = pk;
        }
    __syncthreads();
    {
        u16* ctr = ctx + (qrowb + qv) * DM + h * 64 + hi * 32;
        #pragma unroll
        for (int g = 0; g < 4; ++g) {
            bf16x8 vv = *(const bf16x8*)&eb[qv * 64 + ((hi * 32 + g * 8) ^ ((qv & 7) * 8))];
            *(bf16x8*)(ctr + g * 8) = vv;
        }
    }
}

// ---------- way classifier: logits = out @ wcls + bcls ----------
__global__ __launch_bounds__(256) void cls_kernel(
    const float* __restrict__ outm, const float* __restrict__ wcls,
    const float* __restrict__ bcls, float* __restrict__ dst)
{
    int row = blockIdx.x, t = threadIdx.x;
    const float* xr = outm + (size_t)row * DM;
    float a0 = 0, a1 = 0, a2 = 0, a3 = 0;
    for (int j = t; j < DM; j += 256) {
        float xv = xr[j];
        float4 wv4 = *(const float4*)(const void*)(wcls + (size_t)j * 4);
        a0 += xv * wv4.x; a1 += xv * wv4.y; a2 += xv * wv4.z; a3 += xv * wv4.w;
    }
    #pragma unroll
    for (int k = 1; k < 64; k <<= 1) {
        a0 += __shfl_xor(a0, k); a1 += __shfl_xor(a1, k);
        a2 += __shfl_xor(a2, k); a3 += __shfl_xor(a3, k);
    }
    __shared__ float red[4][4];
    if ((t & 63) == 0) {
        int wid = t >> 6;
        red[wid][0] = a0; red[wid][1] = a1; red[wid][2] = a2; red[wid][3] = a3;
    }
    __syncthreads();
    if (t < 4)
        dst[(size_t)row * 4 + t] =
            red[0][t] + red[1][t] + red[2][t] + red[3][t] + bcls[t];
}

// ---------- launch ----------
extern "C" void kernel_launch(void* const* d_in, const int* in_sizes, int n_in,
                              void* d_out, int out_size, void* d_ws, size_t ws_size,
                              hipStream_t stream) {
    const float* x      = (const float*)d_in[0];
    const int*   wl     = (const int*)d_in[1];        // int inputs are int32
    const float* ln_g   = (const float*)d_in[2];
    const float* ln_b   = (const float*)d_in[3];
    const float* wq     = (const float*)d_in[4];
    const float* bq     = (const float*)d_in[5];
    const float* wk     = (const float*)d_in[6];
    const float* bk     = (const float*)d_in[7];
    const float* wvv    = (const float*)d_in[8];
    const float* bv     = (const float*)d_in[9];
    const float* wo     = (const float*)d_in[10];
    const float* bo     = (const float*)d_in[11];
    const float* wcls   = (const float*)d_in[12];
    const float* bcls   = (const float*)d_in[13];
    const float* w1     = (const float*)d_in[14];
    const float* b1     = (const float*)d_in[15];
    const float* w2     = (const float*)d_in[16];
    const float* b2     = (const float*)d_in[17];
    float* out = (float*)d_out;

    char* ws = (char*)d_ws;
    u16*   xn    = (u16*)  (ws + 0);            // 12,582,912 B
    u16*   qkv   = (u16*)  (ws + 12582912);     // 37,748,736 B
    u16*   hbuf  = (u16*)  (ws + 0);            // reuse xn+qkv (50,331,648 B)
    u16*   ctx   = (u16*)  (ws + 50331648);     // 12,582,912
    u16*   outb  = (u16*)  (ws + 62914560);     // 12,582,912
    u16*   wqkvt = (u16*)  (ws + 75497472);     // 3,538,944
    u16*   wot   = (u16*)  (ws + 79036416);     // 1,179,648
    u16*   w1t   = (u16*)  (ws + 80216064);     // 18,874,368
    u16*   w2t   = (u16*)  (ws + 99090432);     // 18,874,368
    float* bqkv  = (float*)(ws + 117964800);    // 9,216
    int*   perm  = (int*)  (ws + 117974016);    // 32,768
    int*   eoff  = (int*)  (ws + 118006784);    // 32
    int4*  fmap  = (int4*) (ws + 118006816);    // 1,152 (72 entries)
    u16*   vT    = (u16*)  (ws + 118007968);    // 12,582,912 (16B aligned)
    float* outf  = out;                          // f32 'out' lives in d_out ffn
                                                 // region; cls reads it BEFORE
                                                 // FFN2 scatter-overwrites it.

    route_kernel<<<1, 256, 0, stream>>>(wl, perm, eoff, fmap);
    concat_bias_kernel<<<9, 256, 0, stream>>>(bq, bk, bv, bqkv);
    dim3 tb(32, 8);
    transpose_bf16<<<dim3(24, 24, 1), tb, 0, stream>>>(wq,  wqkvt,             768, 768);
    transpose_bf16<<<dim3(24, 24, 1), tb, 0, stream>>>(wk,  wqkvt + 768 * 768, 768, 768);
    transpose_bf16<<<dim3(24, 24, 1), tb, 0, stream>>>(wvv, wqkvt + 2 * 768 * 768, 768, 768);
    transpose_bf16<<<dim3(24, 24, 1), tb, 0, stream>>>(wo,  wot, 768, 768);
    transpose_bf16<<<dim3(96, 24, 4), tb, 0, stream>>>(w1,  w1t, 768, 3072);
    transpose_bf16<<<dim3(24, 96, 4), tb, 0, stream>>>(w2,  w2t, 3072, 768);
    ln_kernel<<<MB_TOK, 256, 0, stream>>>(x, ln_g, ln_b, xn);

    // QKV: [8192,768] x [768,2304]  grid = 8 xcd * 8 bt * 18 tn
    gemm_bt_kernel<0, false, false, false, true><<<1152, 256, 0, stream>>>(
        xn, wqkvt, bqkv, nullptr, nullptr, qkv, 64, 2304, 768, 18, nullptr, nullptr);

    // V transpose for attention PV operand
    vT_kernel<<<dim3(64, 2, 48), tb, 0, stream>>>(qkv, vT);

    attn_kernel<<<768, 256, 0, stream>>>(qkv, vT, ctx);

    // WO + residual: out = ctx@wo + bo + x   grid = 8*8*6
    gemm_bt_kernel<0, false, true, true, true><<<384, 256, 0, stream>>>(
        ctx, wot, bo, x, outf, outb, 64, 768, 768, 6, nullptr, nullptr);

    cls_kernel<<<MB_TOK, 256, 0, stream>>>(outf, wcls, bcls, out + (size_t)MB_TOK * DM);

    // FFN1: gathered rows, relu -> h   grid = 8*9*24
    gemm_bt_kernel<1, true, false, false, true><<<1728, 256, 0, stream>>>(
        outb, w1t, b1, nullptr, nullptr, hbuf, 72, DFF, 768, 24, perm, fmap);

    // FFN2: h -> scatter into d_out   grid = 8*9*6
    gemm_bt_kernel<2, false, false, true, false><<<432, 256, 0, stream>>>(
        hbuf, w2t, b2, nullptr, out, nullptr, 72, 768, DFF, 6, perm, fmap);
}